// Round 4
// baseline (554.359 us; speedup 1.0000x reference)
//
#include <hip/hip_runtime.h>

// DPP controls (gfx9 encoding for __builtin_amdgcn_update_dpp):
//   quad_perm [1,0,3,2] = lane^1, [2,3,0,1] = lane^2, [3,2,1,0] = lane^3
//   ROW_HALF_MIRROR (0x141) = lane^7 within each 8-lane half-row
//   ROW_ROR:8      (0x128) = lane^8 within each 16-lane row
#define DPP_XOR1 0xB1
#define DPP_XOR2 0x4E
#define DPP_XOR3 0x1B
#define DPP_XOR7 0x141
#define DPP_XOR8 0x128

// Instrumented round: REP=10 keeps the kernel above the ~95us harness fill
// dispatches so rocprof top-k shows its counters. Next round strips REP.
#define REP 10

template <int CTRL>
__device__ __forceinline__ float dppf(float x) {
  return __int_as_float(__builtin_amdgcn_update_dpp(
      0, __float_as_int(x), CTRL, 0xF, 0xF, true));
}

__device__ __forceinline__ float fast_tanh(float x) {
  // tanh(x) = 1 - 2/(e^{2x}+1)
  float e = __expf(2.0f * x);
  float r = __builtin_amdgcn_rcpf(e + 1.0f);
  return fmaf(-2.0f, r, 1.0f);
}

// B=16384, D=2472, N=50, H=4.
// 16 lanes per row (one lane per k-element of the 16-wide gathered slice),
// 256 threads/block -> 16 rows/block, 1024 blocks -> 4 waves/SIMD (latency fix).
__global__ __launch_bounds__(256, 4) void rec_policy_kernel(
    const float* __restrict__ x,
    const float* __restrict__ Wcf1, const float* __restrict__ bcf1,
    const float* __restrict__ Wihu, const float* __restrict__ bihu,
    const float* __restrict__ Whhu, const float* __restrict__ bhhu,
    const float* __restrict__ Wfc1, const float* __restrict__ bfc1,
    const float* __restrict__ Wfc2, const float* __restrict__ bfc2,
    const float* __restrict__ Wihd, const float* __restrict__ bihd,
    const float* __restrict__ Whhd, const float* __restrict__ bhhd,
    const float* __restrict__ Wout, const float* __restrict__ bout,
    float* __restrict__ out)
{
  const int tid  = threadIdx.x;
  const int k16  = tid & 15;            // k-element this lane owns (0..15)
  const int l4   = tid & 3;             // h-component this lane owns (0..3)
  const int b    = blockIdx.x * 16 + (tid >> 4);
  const float* __restrict__ xr = x + (size_t)b * 2472;

  // ---------------- weight prep (static-indexed registers) ----------------
  // Folded Wc = W_ih_up @ W_cf1 (4x16); lane holds column k16 for all 4 rows.
  float wcol[4];
  #pragma unroll
  for (int m = 0; m < 4; ++m) {
    wcol[m] = Wihu[m * 4 + 0] * Wcf1[k16]
            + Wihu[m * 4 + 1] * Wcf1[16 + k16]
            + Wihu[m * 4 + 2] * Wcf1[32 + k16]
            + Wihu[m * 4 + 3] * Wcf1[48 + k16];
  }
  // total bias for this lane's h-component m = l4
  float btot = bihu[l4] + bhhu[l4]
             + Wihu[l4 * 4 + 0] * bcf1[0] + Wihu[l4 * 4 + 1] * bcf1[1]
             + Wihu[l4 * 4 + 2] * bcf1[2] + Wihu[l4 * 4 + 3] * bcf1[3];
  float whhp[4];
  #pragma unroll
  for (int j = 0; j < 4; ++j) whhp[j] = Whhu[l4 * 4 + (l4 ^ j)];

  float wfc1o[7], wfc1h[4], wfc2p[4];
  #pragma unroll
  for (int k = 0; k < 7; ++k) wfc1o[k] = Wfc1[l4 * 11 + k];
  #pragma unroll
  for (int j = 0; j < 4; ++j) wfc1h[j] = Wfc1[l4 * 11 + 7 + (l4 ^ j)];
  #pragma unroll
  for (int j = 0; j < 4; ++j) wfc2p[j] = Wfc2[l4 * 4 + (l4 ^ j)];
  const float bfc1l = bfc1[l4];
  const float bfc2l = bfc2[l4];

  float wid[4], whd[4], wo[4];
  #pragma unroll
  for (int j = 0; j < 4; ++j) {
    wid[j] = Wihd[l4 * 4 + (l4 ^ j)];
    whd[j] = Whhd[l4 * 4 + (l4 ^ j)];
    wo[j]  = Wout[l4 ^ j];
  }
  const float bdn = bihd[l4] + bhhd[l4];
  const float wo4 = Wout[4];
  const float bo  = bout[0];

  const bool s1  = (l4 & 1) != 0;
  const bool s2b = (l4 & 2) != 0;

  // per-lane load address: k<8 -> cols 7+50i+k ; k>=8 -> cols 407+8i+(k-8)
  const float* __restrict__ basep = (k16 < 8) ? (xr + 7 + k16) : (xr + 399 + k16);
  const int strd = (k16 < 8) ? 50 : 8;

  #pragma unroll 1
  for (int rep = 0; rep < REP; ++rep) {
    asm volatile("" ::: "memory");   // defeat cross-rep load CSE only

    // ---------------- up scan: i = 49 .. 0 ----------------
    float h = 0.0f;
    float hup[7];

    #pragma unroll
    for (int i = 49; i >= 0; --i) {
      float v = basep[strd * i];     // 1 coalesced dword per lane

      // products for all 4 h-components over this lane's k
      float p0 = wcol[0] * v;
      float p1 = wcol[1] * v;
      float p2 = wcol[2] * v;
      float p3 = wcol[3] * v;

      // 16-lane butterfly all-reduce (pure DPP): xor1, xor2, xor7, xor8
      p0 += dppf<DPP_XOR1>(p0); p1 += dppf<DPP_XOR1>(p1);
      p2 += dppf<DPP_XOR1>(p2); p3 += dppf<DPP_XOR1>(p3);
      p0 += dppf<DPP_XOR2>(p0); p1 += dppf<DPP_XOR2>(p1);
      p2 += dppf<DPP_XOR2>(p2); p3 += dppf<DPP_XOR2>(p3);
      p0 += dppf<DPP_XOR7>(p0); p1 += dppf<DPP_XOR7>(p1);
      p2 += dppf<DPP_XOR7>(p2); p3 += dppf<DPP_XOR7>(p3);
      p0 += dppf<DPP_XOR8>(p0); p1 += dppf<DPP_XOR8>(p1);
      p2 += dppf<DPP_XOR8>(p2); p3 += dppf<DPP_XOR8>(p3);

      float sel = s2b ? (s1 ? p3 : p2) : (s1 ? p1 : p0);

      // h-recurrence (quad-local: quads hold identical replicated h)
      float g1 = dppf<DPP_XOR1>(h);
      float g2 = dppf<DPP_XOR2>(h);
      float g3 = dppf<DPP_XOR3>(h);
      float s = sel + btot;
      s = fmaf(whhp[0], h,  s);
      s = fmaf(whhp[1], g1, s);
      s = fmaf(whhp[2], g2, s);
      s = fmaf(whhp[3], g3, s);
      h = fast_tanh(s);

      if (i < 7) hup[i] = h;
    }

    // ---------------- fc stage (redundant across quads, quad-local DPP) -----
    float pre1 = bfc1l;
    #pragma unroll
    for (int k = 0; k < 7; ++k) pre1 = fmaf(wfc1o[k], xr[k], pre1);
    {
      float g1 = dppf<DPP_XOR1>(h);
      float g2 = dppf<DPP_XOR2>(h);
      float g3 = dppf<DPP_XOR3>(h);
      pre1 = fmaf(wfc1h[0], h,  pre1);
      pre1 = fmaf(wfc1h[1], g1, pre1);
      pre1 = fmaf(wfc1h[2], g2, pre1);
      pre1 = fmaf(wfc1h[3], g3, pre1);
    }
    float t1 = fast_tanh(pre1);
    float acc2 = bfc2l;
    {
      float g1 = dppf<DPP_XOR1>(t1);
      float g2 = dppf<DPP_XOR2>(t1);
      float g3 = dppf<DPP_XOR3>(t1);
      acc2 = fmaf(wfc2p[0], t1, acc2);
      acc2 = fmaf(wfc2p[1], g1, acc2);
      acc2 = fmaf(wfc2p[2], g2, acc2);
      acc2 = fmaf(wfc2p[3], g3, acc2);
    }
    h = fast_tanh(acc2);

    // ---------------- down scan: t = 0..6 ----------------
    #pragma unroll
    for (int t = 0; t < 7; ++t) {
      float g1 = dppf<DPP_XOR1>(h);
      float g2 = dppf<DPP_XOR2>(h);
      float g3 = dppf<DPP_XOR3>(h);
      float act = fmaf(wo4, xr[7 + t], bo);
      act = fmaf(wo[0], h,  act);
      act = fmaf(wo[1], g1, act);
      act = fmaf(wo[2], g2, act);
      act = fmaf(wo[3], g3, act);
      if (k16 == 0) out[(size_t)b * 7 + t] = act;

      float hu = hup[t];
      float u1 = dppf<DPP_XOR1>(hu);
      float u2 = dppf<DPP_XOR2>(hu);
      float u3 = dppf<DPP_XOR3>(hu);
      float s = bdn;
      s = fmaf(wid[0], hu, s);
      s = fmaf(wid[1], u1, s);
      s = fmaf(wid[2], u2, s);
      s = fmaf(wid[3], u3, s);
      s = fmaf(whd[0], h,  s);
      s = fmaf(whd[1], g1, s);
      s = fmaf(whd[2], g2, s);
      s = fmaf(whd[3], g3, s);
      h = fast_tanh(s);
    }
  }
}

extern "C" void kernel_launch(void* const* d_in, const int* in_sizes, int n_in,
                              void* d_out, int out_size, void* d_ws, size_t ws_size,
                              hipStream_t stream) {
  (void)in_sizes; (void)n_in; (void)d_ws; (void)ws_size; (void)out_size;
  rec_policy_kernel<<<dim3(1024), dim3(256), 0, stream>>>(
      (const float*)d_in[0],
      (const float*)d_in[1],  (const float*)d_in[2],
      (const float*)d_in[3],  (const float*)d_in[4],
      (const float*)d_in[5],  (const float*)d_in[6],
      (const float*)d_in[7],  (const float*)d_in[8],
      (const float*)d_in[9],  (const float*)d_in[10],
      (const float*)d_in[11], (const float*)d_in[12],
      (const float*)d_in[13], (const float*)d_in[14],
      (const float*)d_in[15], (const float*)d_in[16],
      (float*)d_out);
}

// Round 5
// 420.927 us; speedup vs baseline: 1.3170x; 1.3170x over previous
//
#include <hip/hip_runtime.h>

// DPP quad_perm controls: lane <- lane^1 / lane^2 / lane^3 within each quad
#define DPP_XOR1 0xB1
#define DPP_XOR2 0x4E
#define DPP_XOR3 0x1B

// Instrumented round: REP=10 for within-probe A/B vs round 4. Strip next round.
#define REP 10

template <int CTRL>
__device__ __forceinline__ float dppf(float x) {
  return __int_as_float(__builtin_amdgcn_update_dpp(
      0, __float_as_int(x), CTRL, 0xF, 0xF, true));
}

// Broadcast quad S to all quads within each 16-lane group.
// ds_swizzle BitMode: src_lane = ((lane & 0x13) | (S<<2)); preserves bits 0,1
// (quarter g = h-row) and bit 4 (row parity), forces quad index = S.
template <int S>
__device__ __forceinline__ float bcast_quad(float v) {
  return __int_as_float(__builtin_amdgcn_ds_swizzle(
      __float_as_int(v), (S << 7) | 0x13));
}

__device__ __forceinline__ float fast_tanh(float x) {
  // tanh(x) = 1 - 2/(e^{2x}+1)
  float e = __expf(2.0f * x);
  float r = __builtin_amdgcn_rcpf(e + 1.0f);
  return fmaf(-2.0f, r, 1.0f);
}

// A-chunks are only 4B-aligned (byte offset 28+200i); packed+aligned(4) makes
// the dwordx4 load legal. Worst case backend splits it -> round-4 behavior.
struct __attribute__((packed, aligned(4))) f4u { float x, y, z, w; };

// one cell update for absolute scan step STEP, consuming quad SGET's sel
#define SUBSTEP(SEL, SGET, STEP)                                           \
  do {                                                                     \
    float bsel = bcast_quad<SGET>(SEL);                                    \
    float q1 = dppf<DPP_XOR1>(h);                                          \
    float q2 = dppf<DPP_XOR2>(h);                                          \
    float q3 = dppf<DPP_XOR3>(h);                                          \
    float sv = bsel + btot;                                                \
    sv = fmaf(whhp[0], h,  sv);                                            \
    sv = fmaf(whhp[1], q1, sv);                                            \
    sv = fmaf(whhp[2], q2, sv);                                            \
    sv = fmaf(whhp[3], q3, sv);                                            \
    h = fast_tanh(sv);                                                     \
    if ((STEP) < 7) hup[(STEP) < 7 ? (STEP) : 0] = h;                      \
  } while (0)

// full superstep SS (SS>=1): quad j handles step (47-4*(SS-1))-j
#define SUPERSTEP(SS)                                                      \
  do {                                                                     \
    f4u v4 = *(const f4u*)pr;                                              \
    float p0 = fmaf(wq[0][0], v4.x, fmaf(wq[0][1], v4.y,                   \
               fmaf(wq[0][2], v4.z, wq[0][3] * v4.w)));                    \
    float p1 = fmaf(wq[1][0], v4.x, fmaf(wq[1][1], v4.y,                   \
               fmaf(wq[1][2], v4.z, wq[1][3] * v4.w)));                    \
    float p2 = fmaf(wq[2][0], v4.x, fmaf(wq[2][1], v4.y,                   \
               fmaf(wq[2][2], v4.z, wq[2][3] * v4.w)));                    \
    float p3 = fmaf(wq[3][0], v4.x, fmaf(wq[3][1], v4.y,                   \
               fmaf(wq[3][2], v4.z, wq[3][3] * v4.w)));                    \
    p0 += dppf<DPP_XOR1>(p0); p1 += dppf<DPP_XOR1>(p1);                    \
    p2 += dppf<DPP_XOR1>(p2); p3 += dppf<DPP_XOR1>(p3);                    \
    p0 += dppf<DPP_XOR2>(p0); p1 += dppf<DPP_XOR2>(p1);                    \
    p2 += dppf<DPP_XOR2>(p2); p3 += dppf<DPP_XOR2>(p3);                    \
    float selo = gb2 ? (gb1 ? p3 : p2) : (gb1 ? p1 : p0);                  \
    SUBSTEP(selo, 0, (47 - 4 * ((SS) - 1) - 0));                           \
    SUBSTEP(selo, 1, (47 - 4 * ((SS) - 1) - 1));                           \
    SUBSTEP(selo, 2, (47 - 4 * ((SS) - 1) - 2));                           \
    SUBSTEP(selo, 3, (47 - 4 * ((SS) - 1) - 3));                           \
    pr -= 4 * strd;                                                        \
  } while (0)

// B=16384, D=2472, N=50, H=4.
// 16 lanes/row as 4x4 (quad j = sub-step, quarter g = lane&3 = h-row).
// One float4 load per lane per 4 scan steps -> 4x bytes in flight per VGPR.
__global__ __launch_bounds__(256, 4) void rec_policy_kernel(
    const float* __restrict__ x,
    const float* __restrict__ Wcf1, const float* __restrict__ bcf1,
    const float* __restrict__ Wihu, const float* __restrict__ bihu,
    const float* __restrict__ Whhu, const float* __restrict__ bhhu,
    const float* __restrict__ Wfc1, const float* __restrict__ bfc1,
    const float* __restrict__ Wfc2, const float* __restrict__ bfc2,
    const float* __restrict__ Wihd, const float* __restrict__ bihd,
    const float* __restrict__ Whhd, const float* __restrict__ bhhd,
    const float* __restrict__ Wout, const float* __restrict__ bout,
    float* __restrict__ out)
{
  const int tid = threadIdx.x;
  const int k16 = tid & 15;             // lane within row-group
  const int g   = tid & 3;              // quarter AND h-component this lane owns
  const int j   = (tid >> 2) & 3;       // quad index = sub-step offset
  const int b   = blockIdx.x * 16 + (tid >> 4);
  const float* __restrict__ xr = x + (size_t)b * 2472;

  // ---------------- weight prep (all static-indexed registers) ----------------
  // Folded Wc = W_ih_up @ W_cf1 (4x16); lane holds columns 4g..4g+3, all 4 rows.
  float wq[4][4];
  #pragma unroll
  for (int m = 0; m < 4; ++m) {
    #pragma unroll
    for (int c = 0; c < 4; ++c) {
      const int col = 4 * g + c;
      wq[m][c] = Wihu[m * 4 + 0] * Wcf1[col]
               + Wihu[m * 4 + 1] * Wcf1[16 + col]
               + Wihu[m * 4 + 2] * Wcf1[32 + col]
               + Wihu[m * 4 + 3] * Wcf1[48 + col];
    }
  }
  const float btot = bihu[g] + bhhu[g]
      + Wihu[g * 4 + 0] * bcf1[0] + Wihu[g * 4 + 1] * bcf1[1]
      + Wihu[g * 4 + 2] * bcf1[2] + Wihu[g * 4 + 3] * bcf1[3];
  float whhp[4];
  #pragma unroll
  for (int t = 0; t < 4; ++t) whhp[t] = Whhu[g * 4 + (g ^ t)];

  float wfc1o[7], wfc1h[4], wfc2p[4];
  #pragma unroll
  for (int k = 0; k < 7; ++k) wfc1o[k] = Wfc1[g * 11 + k];
  #pragma unroll
  for (int t = 0; t < 4; ++t) wfc1h[t] = Wfc1[g * 11 + 7 + (g ^ t)];
  #pragma unroll
  for (int t = 0; t < 4; ++t) wfc2p[t] = Wfc2[g * 4 + (g ^ t)];
  const float bfc1l = bfc1[g];
  const float bfc2l = bfc2[g];

  float wid[4], whd[4], wo[4];
  #pragma unroll
  for (int t = 0; t < 4; ++t) {
    wid[t] = Wihd[g * 4 + (g ^ t)];
    whd[t] = Whhd[g * 4 + (g ^ t)];
    wo[t]  = Wout[g ^ t];
  }
  const float bdn = bihd[g] + bhhd[g];
  const float wo4 = Wout[4];
  const float bo  = bout[0];

  const bool gb1 = (g & 1) != 0;
  const bool gb2 = (g & 2) != 0;

  // per-lane base pointer & per-step stride (floats)
  const int strd = (g < 2) ? 50 : 8;
  const float* __restrict__ baseA =
      xr + ((g < 2) ? (7 + 4 * g) : (407 + 4 * (g - 2)));
  // superstep 0 covers steps {49,48}: quads 0,1 -> 49,48; quads 2,3 duplicate
  const float* __restrict__ p_ss0 = baseA + (size_t)strd * (49 - (j & 1));
  // supersteps 1..12: quad j handles step (47-4*(ss-1))-j
  const float* __restrict__ base47 = baseA + (size_t)strd * (47 - j);

  #pragma unroll 1
  for (int rep = 0; rep < REP; ++rep) {
    asm volatile("" ::: "memory");   // defeat cross-rep load CSE only

    float h = 0.0f;
    float hup[7];
    const float* pr = base47;

    // ---- superstep 0: steps 49,48 ----
    {
      f4u v4 = *(const f4u*)p_ss0;
      float p0 = fmaf(wq[0][0], v4.x, fmaf(wq[0][1], v4.y,
                 fmaf(wq[0][2], v4.z, wq[0][3] * v4.w)));
      float p1 = fmaf(wq[1][0], v4.x, fmaf(wq[1][1], v4.y,
                 fmaf(wq[1][2], v4.z, wq[1][3] * v4.w)));
      float p2 = fmaf(wq[2][0], v4.x, fmaf(wq[2][1], v4.y,
                 fmaf(wq[2][2], v4.z, wq[2][3] * v4.w)));
      float p3 = fmaf(wq[3][0], v4.x, fmaf(wq[3][1], v4.y,
                 fmaf(wq[3][2], v4.z, wq[3][3] * v4.w)));
      p0 += dppf<DPP_XOR1>(p0); p1 += dppf<DPP_XOR1>(p1);
      p2 += dppf<DPP_XOR1>(p2); p3 += dppf<DPP_XOR1>(p3);
      p0 += dppf<DPP_XOR2>(p0); p1 += dppf<DPP_XOR2>(p1);
      p2 += dppf<DPP_XOR2>(p2); p3 += dppf<DPP_XOR2>(p3);
      float selo = gb2 ? (gb1 ? p3 : p2) : (gb1 ? p1 : p0);
      SUBSTEP(selo, 0, 49);
      SUBSTEP(selo, 1, 48);
    }

    // ---- supersteps 1..12: steps 47..0 ----
    SUPERSTEP(1);  SUPERSTEP(2);  SUPERSTEP(3);  SUPERSTEP(4);
    SUPERSTEP(5);  SUPERSTEP(6);  SUPERSTEP(7);  SUPERSTEP(8);
    SUPERSTEP(9);  SUPERSTEP(10); SUPERSTEP(11); SUPERSTEP(12);

    // ---------------- fc stage ----------------
    float pre1 = bfc1l;
    #pragma unroll
    for (int k = 0; k < 7; ++k) pre1 = fmaf(wfc1o[k], xr[k], pre1);
    {
      float q1 = dppf<DPP_XOR1>(h);
      float q2 = dppf<DPP_XOR2>(h);
      float q3 = dppf<DPP_XOR3>(h);
      pre1 = fmaf(wfc1h[0], h,  pre1);
      pre1 = fmaf(wfc1h[1], q1, pre1);
      pre1 = fmaf(wfc1h[2], q2, pre1);
      pre1 = fmaf(wfc1h[3], q3, pre1);
    }
    float t1 = fast_tanh(pre1);
    float acc2 = bfc2l;
    {
      float q1 = dppf<DPP_XOR1>(t1);
      float q2 = dppf<DPP_XOR2>(t1);
      float q3 = dppf<DPP_XOR3>(t1);
      acc2 = fmaf(wfc2p[0], t1, acc2);
      acc2 = fmaf(wfc2p[1], q1, acc2);
      acc2 = fmaf(wfc2p[2], q2, acc2);
      acc2 = fmaf(wfc2p[3], q3, acc2);
    }
    h = fast_tanh(acc2);

    // ---------------- down scan: t = 0..6 ----------------
    #pragma unroll
    for (int t = 0; t < 7; ++t) {
      float q1 = dppf<DPP_XOR1>(h);
      float q2 = dppf<DPP_XOR2>(h);
      float q3 = dppf<DPP_XOR3>(h);
      float act = fmaf(wo4, xr[7 + t], bo);
      act = fmaf(wo[0], h,  act);
      act = fmaf(wo[1], q1, act);
      act = fmaf(wo[2], q2, act);
      act = fmaf(wo[3], q3, act);
      if (k16 == 0) out[(size_t)b * 7 + t] = act;

      float hu = hup[t];
      float u1 = dppf<DPP_XOR1>(hu);
      float u2 = dppf<DPP_XOR2>(hu);
      float u3 = dppf<DPP_XOR3>(hu);
      float sv = bdn;
      sv = fmaf(wid[0], hu, sv);
      sv = fmaf(wid[1], u1, sv);
      sv = fmaf(wid[2], u2, sv);
      sv = fmaf(wid[3], u3, sv);
      sv = fmaf(whd[0], h,  sv);
      sv = fmaf(whd[1], q1, sv);
      sv = fmaf(whd[2], q2, sv);
      sv = fmaf(whd[3], q3, sv);
      h = fast_tanh(sv);
    }
  }
}

extern "C" void kernel_launch(void* const* d_in, const int* in_sizes, int n_in,
                              void* d_out, int out_size, void* d_ws, size_t ws_size,
                              hipStream_t stream) {
  (void)in_sizes; (void)n_in; (void)d_ws; (void)ws_size; (void)out_size;
  rec_policy_kernel<<<dim3(1024), dim3(256), 0, stream>>>(
      (const float*)d_in[0],
      (const float*)d_in[1],  (const float*)d_in[2],
      (const float*)d_in[3],  (const float*)d_in[4],
      (const float*)d_in[5],  (const float*)d_in[6],
      (const float*)d_in[7],  (const float*)d_in[8],
      (const float*)d_in[9],  (const float*)d_in[10],
      (const float*)d_in[11], (const float*)d_in[12],
      (const float*)d_in[13], (const float*)d_in[14],
      (const float*)d_in[15], (const float*)d_in[16],
      (float*)d_out);
}

// Round 9
// 250.344 us; speedup vs baseline: 2.2144x; 1.6814x over previous
//
#include <hip/hip_runtime.h>

// DPP quad_perm controls: lane <- lane^1 / lane^2 / lane^3 within each quad
#define DPP_XOR1 0xB1
#define DPP_XOR2 0x4E
#define DPP_XOR3 0x1B

template <int CTRL>
__device__ __forceinline__ float dppf(float x) {
  return __int_as_float(__builtin_amdgcn_update_dpp(
      0, __float_as_int(x), CTRL, 0xF, 0xF, true));
}

// Broadcast quad S to all quads within each 16-lane group.
// ds_swizzle BitMode: src_lane = ((lane & 0x13) | (S<<2)); preserves bits 0,1
// (quarter g = h-row) and bit 4 (row parity), forces quad index = S.
template <int S>
__device__ __forceinline__ float bcast_quad(float v) {
  return __int_as_float(__builtin_amdgcn_ds_swizzle(
      __float_as_int(v), (S << 7) | 0x13));
}

__device__ __forceinline__ float fast_tanh(float x) {
  // tanh(x) = 1 - 2/(e^{2x}+1)
  float e = __expf(2.0f * x);
  float r = __builtin_amdgcn_rcpf(e + 1.0f);
  return fmaf(-2.0f, r, 1.0f);
}

// A-chunks are only 4B-aligned (byte offset 28+200i); packed+aligned(4) keeps
// the 16B load legal at dword alignment.
struct __attribute__((packed, aligned(4))) f4u { float x, y, z, w; };

// one cell update for absolute scan step STEP, consuming quad SGET's sel
#define SUBSTEP(SEL, SGET, STEP)                                           \
  do {                                                                     \
    float bsel = bcast_quad<SGET>(SEL);                                    \
    float q1 = dppf<DPP_XOR1>(h);                                          \
    float q2 = dppf<DPP_XOR2>(h);                                          \
    float q3 = dppf<DPP_XOR3>(h);                                          \
    float sv = bsel + btot;                                                \
    sv = fmaf(whhp[0], h,  sv);                                            \
    sv = fmaf(whhp[1], q1, sv);                                            \
    sv = fmaf(whhp[2], q2, sv);                                            \
    sv = fmaf(whhp[3], q3, sv);                                            \
    h = fast_tanh(sv);                                                     \
    if ((STEP) < 7) hup[(STEP) < 7 ? (STEP) : 0] = h;                      \
  } while (0)

// full superstep SS (SS>=1) consuming pre-loaded vector V4:
// quad j handles step (47-4*(SS-1))-j
#define SUPERSTEP_V(V4, SS)                                                \
  do {                                                                     \
    float p0 = fmaf(wq[0][0], (V4).x, fmaf(wq[0][1], (V4).y,               \
               fmaf(wq[0][2], (V4).z, wq[0][3] * (V4).w)));                \
    float p1 = fmaf(wq[1][0], (V4).x, fmaf(wq[1][1], (V4).y,               \
               fmaf(wq[1][2], (V4).z, wq[1][3] * (V4).w)));                \
    float p2 = fmaf(wq[2][0], (V4).x, fmaf(wq[2][1], (V4).y,               \
               fmaf(wq[2][2], (V4).z, wq[2][3] * (V4).w)));                \
    float p3 = fmaf(wq[3][0], (V4).x, fmaf(wq[3][1], (V4).y,               \
               fmaf(wq[3][2], (V4).z, wq[3][3] * (V4).w)));                \
    p0 += dppf<DPP_XOR1>(p0); p1 += dppf<DPP_XOR1>(p1);                    \
    p2 += dppf<DPP_XOR1>(p2); p3 += dppf<DPP_XOR1>(p3);                    \
    p0 += dppf<DPP_XOR2>(p0); p1 += dppf<DPP_XOR2>(p1);                    \
    p2 += dppf<DPP_XOR2>(p2); p3 += dppf<DPP_XOR2>(p3);                    \
    float selo = gb2 ? (gb1 ? p3 : p2) : (gb1 ? p1 : p0);                  \
    SUBSTEP(selo, 0, (47 - 4 * ((SS) - 1) - 0));                           \
    SUBSTEP(selo, 1, (47 - 4 * ((SS) - 1) - 1));                           \
    SUBSTEP(selo, 2, (47 - 4 * ((SS) - 1) - 2));                           \
    SUBSTEP(selo, 3, (47 - 4 * ((SS) - 1) - 3));                           \
  } while (0)

// B=16384, D=2472, N=50, H=4.
// 16 lanes/row as 4x4 (quad j = sub-step, quarter g = lane&3 = h-row).
// All 13 float4 loads are issued up-front into named registers
// (13 KB in flight per wave) before the serial 50-step scan consumes them.
__global__ __launch_bounds__(256, 4) void rec_policy_kernel(
    const float* __restrict__ x,
    const float* __restrict__ Wcf1, const float* __restrict__ bcf1,
    const float* __restrict__ Wihu, const float* __restrict__ bihu,
    const float* __restrict__ Whhu, const float* __restrict__ bhhu,
    const float* __restrict__ Wfc1, const float* __restrict__ bfc1,
    const float* __restrict__ Wfc2, const float* __restrict__ bfc2,
    const float* __restrict__ Wihd, const float* __restrict__ bihd,
    const float* __restrict__ Whhd, const float* __restrict__ bhhd,
    const float* __restrict__ Wout, const float* __restrict__ bout,
    float* __restrict__ out)
{
  const int tid = threadIdx.x;
  const int k16 = tid & 15;             // lane within row-group
  const int g   = tid & 3;              // quarter AND h-component this lane owns
  const int j   = (tid >> 2) & 3;       // quad index = sub-step offset
  const int b   = blockIdx.x * 16 + (tid >> 4);
  const float* __restrict__ xr = x + (size_t)b * 2472;

  // ---- burst-issue all 13 loads into named registers (13 KB/wave) ----
  const int strd = (g < 2) ? 50 : 8;
  const float* __restrict__ baseA =
      xr + ((g < 2) ? (7 + 4 * g) : (407 + 4 * (g - 2)));
  // superstep 0 covers steps {49,48}: quads 0,1 -> 49,48; quads 2,3 duplicate
  const float* __restrict__ p_ss0 = baseA + (size_t)strd * (49 - (j & 1));
  // supersteps 1..12: quad j handles step (47-4*(ss-1))-j
  const float* __restrict__ base47 = baseA + (size_t)strd * (47 - j);
  const int s4 = 4 * strd;

  f4u u0  = *(const f4u*)(p_ss0);
  f4u u1  = *(const f4u*)(base47);
  f4u u2  = *(const f4u*)(base47 - 1 * s4);
  f4u u3  = *(const f4u*)(base47 - 2 * s4);
  f4u u4  = *(const f4u*)(base47 - 3 * s4);
  f4u u5  = *(const f4u*)(base47 - 4 * s4);
  f4u u6  = *(const f4u*)(base47 - 5 * s4);
  f4u u7  = *(const f4u*)(base47 - 6 * s4);
  f4u u8  = *(const f4u*)(base47 - 7 * s4);
  f4u u9  = *(const f4u*)(base47 - 8 * s4);
  f4u u10 = *(const f4u*)(base47 - 9 * s4);
  f4u u11 = *(const f4u*)(base47 - 10 * s4);
  f4u u12 = *(const f4u*)(base47 - 11 * s4);

  // ---------------- weight prep (all static-indexed registers) ----------------
  float wq[4][4];
  #pragma unroll
  for (int m = 0; m < 4; ++m) {
    #pragma unroll
    for (int c = 0; c < 4; ++c) {
      const int col = 4 * g + c;
      wq[m][c] = Wihu[m * 4 + 0] * Wcf1[col]
               + Wihu[m * 4 + 1] * Wcf1[16 + col]
               + Wihu[m * 4 + 2] * Wcf1[32 + col]
               + Wihu[m * 4 + 3] * Wcf1[48 + col];
    }
  }
  const float btot = bihu[g] + bhhu[g]
      + Wihu[g * 4 + 0] * bcf1[0] + Wihu[g * 4 + 1] * bcf1[1]
      + Wihu[g * 4 + 2] * bcf1[2] + Wihu[g * 4 + 3] * bcf1[3];
  float whhp[4];
  #pragma unroll
  for (int t = 0; t < 4; ++t) whhp[t] = Whhu[g * 4 + (g ^ t)];

  float wfc1o[7], wfc1h[4], wfc2p[4];
  #pragma unroll
  for (int k = 0; k < 7; ++k) wfc1o[k] = Wfc1[g * 11 + k];
  #pragma unroll
  for (int t = 0; t < 4; ++t) wfc1h[t] = Wfc1[g * 11 + 7 + (g ^ t)];
  #pragma unroll
  for (int t = 0; t < 4; ++t) wfc2p[t] = Wfc2[g * 4 + (g ^ t)];
  const float bfc1l = bfc1[g];
  const float bfc2l = bfc2[g];

  float wid[4], whd[4], wo[4];
  #pragma unroll
  for (int t = 0; t < 4; ++t) {
    wid[t] = Wihd[g * 4 + (g ^ t)];
    whd[t] = Whhd[g * 4 + (g ^ t)];
    wo[t]  = Wout[g ^ t];
  }
  const float bdn = bihd[g] + bhhd[g];
  const float wo4 = Wout[4];
  const float bo  = bout[0];

  const bool gb1 = (g & 1) != 0;
  const bool gb2 = (g & 2) != 0;

  float h = 0.0f;
  float hup[7];

  // ---- superstep 0: steps 49,48 (consumes u0) ----
  {
    float p0 = fmaf(wq[0][0], u0.x, fmaf(wq[0][1], u0.y,
               fmaf(wq[0][2], u0.z, wq[0][3] * u0.w)));
    float p1 = fmaf(wq[1][0], u0.x, fmaf(wq[1][1], u0.y,
               fmaf(wq[1][2], u0.z, wq[1][3] * u0.w)));
    float p2 = fmaf(wq[2][0], u0.x, fmaf(wq[2][1], u0.y,
               fmaf(wq[2][2], u0.z, wq[2][3] * u0.w)));
    float p3 = fmaf(wq[3][0], u0.x, fmaf(wq[3][1], u0.y,
               fmaf(wq[3][2], u0.z, wq[3][3] * u0.w)));
    p0 += dppf<DPP_XOR1>(p0); p1 += dppf<DPP_XOR1>(p1);
    p2 += dppf<DPP_XOR1>(p2); p3 += dppf<DPP_XOR1>(p3);
    p0 += dppf<DPP_XOR2>(p0); p1 += dppf<DPP_XOR2>(p1);
    p2 += dppf<DPP_XOR2>(p2); p3 += dppf<DPP_XOR2>(p3);
    float selo = gb2 ? (gb1 ? p3 : p2) : (gb1 ? p1 : p0);
    SUBSTEP(selo, 0, 49);
    SUBSTEP(selo, 1, 48);
  }

  // ---- supersteps 1..12: steps 47..0 ----
  SUPERSTEP_V(u1, 1);   SUPERSTEP_V(u2, 2);   SUPERSTEP_V(u3, 3);
  SUPERSTEP_V(u4, 4);   SUPERSTEP_V(u5, 5);   SUPERSTEP_V(u6, 6);
  SUPERSTEP_V(u7, 7);   SUPERSTEP_V(u8, 8);   SUPERSTEP_V(u9, 9);
  SUPERSTEP_V(u10, 10); SUPERSTEP_V(u11, 11); SUPERSTEP_V(u12, 12);

  // ---------------- fc stage ----------------
  float pre1 = bfc1l;
  #pragma unroll
  for (int k = 0; k < 7; ++k) pre1 = fmaf(wfc1o[k], xr[k], pre1);
  {
    float q1 = dppf<DPP_XOR1>(h);
    float q2 = dppf<DPP_XOR2>(h);
    float q3 = dppf<DPP_XOR3>(h);
    pre1 = fmaf(wfc1h[0], h,  pre1);
    pre1 = fmaf(wfc1h[1], q1, pre1);
    pre1 = fmaf(wfc1h[2], q2, pre1);
    pre1 = fmaf(wfc1h[3], q3, pre1);
  }
  float t1 = fast_tanh(pre1);
  float acc2 = bfc2l;
  {
    float q1 = dppf<DPP_XOR1>(t1);
    float q2 = dppf<DPP_XOR2>(t1);
    float q3 = dppf<DPP_XOR3>(t1);
    acc2 = fmaf(wfc2p[0], t1, acc2);
    acc2 = fmaf(wfc2p[1], q1, acc2);
    acc2 = fmaf(wfc2p[2], q2, acc2);
    acc2 = fmaf(wfc2p[3], q3, acc2);
  }
  h = fast_tanh(acc2);

  // ---------------- down scan: t = 0..6 ----------------
  #pragma unroll
  for (int t = 0; t < 7; ++t) {
    float q1 = dppf<DPP_XOR1>(h);
    float q2 = dppf<DPP_XOR2>(h);
    float q3 = dppf<DPP_XOR3>(h);
    float act = fmaf(wo4, xr[7 + t], bo);
    act = fmaf(wo[0], h,  act);
    act = fmaf(wo[1], q1, act);
    act = fmaf(wo[2], q2, act);
    act = fmaf(wo[3], q3, act);
    if (k16 == 0) out[(size_t)b * 7 + t] = act;

    float hu = hup[t];
    float u1d = dppf<DPP_XOR1>(hu);
    float u2d = dppf<DPP_XOR2>(hu);
    float u3d = dppf<DPP_XOR3>(hu);
    float sv = bdn;
    sv = fmaf(wid[0], hu, sv);
    sv = fmaf(wid[1], u1d, sv);
    sv = fmaf(wid[2], u2d, sv);
    sv = fmaf(wid[3], u3d, sv);
    sv = fmaf(whd[0], h,  sv);
    sv = fmaf(whd[1], q1, sv);
    sv = fmaf(whd[2], q2, sv);
    sv = fmaf(whd[3], q3, sv);
    h = fast_tanh(sv);
  }
}

extern "C" void kernel_launch(void* const* d_in, const int* in_sizes, int n_in,
                              void* d_out, int out_size, void* d_ws, size_t ws_size,
                              hipStream_t stream) {
  (void)in_sizes; (void)n_in; (void)d_ws; (void)ws_size; (void)out_size;
  rec_policy_kernel<<<dim3(1024), dim3(256), 0, stream>>>(
      (const float*)d_in[0],
      (const float*)d_in[1],  (const float*)d_in[2],
      (const float*)d_in[3],  (const float*)d_in[4],
      (const float*)d_in[5],  (const float*)d_in[6],
      (const float*)d_in[7],  (const float*)d_in[8],
      (const float*)d_in[9],  (const float*)d_in[10],
      (const float*)d_in[11], (const float*)d_in[12],
      (const float*)d_in[13], (const float*)d_in[14],
      (const float*)d_in[15], (const float*)d_in[16],
      (float*)d_out);
}